// Round 18
// baseline (200.034 us; speedup 1.0000x reference)
//
#include <hip/hip_runtime.h>
#include <hip/hip_bf16.h>

#define NBT 8192      // B*T
#define NF  16
#define ND  256
#define NH  256
#define N2D 512

typedef short bf16x8 __attribute__((ext_vector_type(8)));
typedef float f32x4 __attribute__((ext_vector_type(4)));
typedef unsigned short u16x8 __attribute__((ext_vector_type(8)));

__device__ __forceinline__ float bf2f(unsigned short u) {
  return __uint_as_float(((unsigned)u) << 16);
}
__device__ __forceinline__ unsigned short f2bf(float f) {
  unsigned u = __float_as_uint(f);
  return (unsigned short)((u + 0x7FFFu + ((u >> 16) & 1u)) >> 16);
}

#define GLOAD16(src, dst)                                                     \
  __builtin_amdgcn_global_load_lds(                                           \
      (const __attribute__((address_space(1))) unsigned int*)(src),           \
      (__attribute__((address_space(3))) unsigned int*)(dst), 16, 0, 0)

// ---------------------------------------------------------------------------
// Merged prep: z<64 -> weight transpose+cast slices (validated r5-r17);
// z in {64,65} -> weight-GRN softmax row-blocks (validated r1-r17).
// Both paths use 256 threads; LDS = union (wgrn's 32 KB dominates).
// ---------------------------------------------------------------------------
__global__ __launch_bounds__(256) void prep_kernel(
    const float* __restrict__ fc1_w, const float* __restrict__ fc2_w,
    const float* __restrict__ glu_w, unsigned short* __restrict__ fc1t,
    unsigned short* __restrict__ fc2t, unsigned short* __restrict__ glut,
    const float* __restrict__ x, const float* __restrict__ fw1,
    const float* __restrict__ fb1, const float* __restrict__ fw2,
    const float* __restrict__ fb2, const float* __restrict__ gwt,
    const float* __restrict__ gbt, const float* __restrict__ lng,
    const float* __restrict__ lnb, float* __restrict__ wout) {
  __shared__ float lds_f[8192];  // wgrn: w1t[4096]+w2s[4096]; transp: tile
  const int bz = blockIdx.z;
  if (bz < 64) {
    // ---------------- transpose path ----------------
    float(*tile)[33] = (float(*)[33])lds_f;
    const int which = bz >> 4;
    const int f     = bz & 15;
    const float* src;
    unsigned short* dst;
    int K, N, bx = blockIdx.x;
    if (which == 0)      { src = fc1_w; dst = fc1t; K = ND; N = NH; }
    else if (which == 1) { src = fc2_w; dst = fc2t; K = NH; N = ND; }
    else                 { src = glu_w; dst = glut; K = ND; N = N2D;
                           bx += (which == 3) ? 8 : 0; }
    if (bx * 32 >= N) return;
    const float* s = src + (size_t)f * K * N;
    unsigned short* d = dst + (size_t)f * K * N;
    const int k0 = blockIdx.y * 32, n0 = bx * 32;
    const int tx = threadIdx.x & 31, ty = threadIdx.x >> 5;
#pragma unroll
    for (int i = 0; i < 32; i += 8)
      tile[ty + i][tx] = s[(size_t)(k0 + ty + i) * N + n0 + tx];
    __syncthreads();
#pragma unroll
    for (int i = 0; i < 32; i += 8)
      d[(size_t)(n0 + ty + i) * K + k0 + tx] = f2bf(tile[tx][ty + i]);
    return;
  }
  // ---------------- wgrn path ----------------
  float* w1t = lds_f;          // [256*16] [j][f]
  float* w2s = lds_f + 4096;   // [256*16]
  const int blk = (bz - 64) * 128 + blockIdx.y * 16 + blockIdx.x;  // 0..255
  const int tid = threadIdx.x;
  for (int i = tid; i < 4096; i += 256) {
    int ff = i >> 8, j = i & 255;
    w1t[j * 16 + ff] = fw1[i];
    w2s[i] = fw2[i];
  }
  __syncthreads();
  const int sub  = tid & 7;
  const int rowi = tid >> 3;
  const int bt   = blk * 32 + rowi;
  float xr[16];
#pragma unroll
  for (int i = 0; i < 4; ++i)
    *(float4*)&xr[i * 4] = *(const float4*)(x + (size_t)bt * 16 + i * 4);
  float acc2[16];
#pragma unroll
  for (int q = 0; q < 16; ++q) acc2[q] = 0.f;
  for (int j = sub; j < 256; j += 8) {
    float h = fb1[j];
    const float* wr = &w1t[j * 16];
#pragma unroll
    for (int q = 0; q < 16; ++q) h = fmaf(xr[q], wr[q], h);
    h = h > 0.f ? h : expm1f(h);
    const float* w2r = &w2s[j * 16];
#pragma unroll
    for (int q = 0; q < 16; ++q) acc2[q] = fmaf(h, w2r[q], acc2[q]);
  }
#pragma unroll
  for (int off = 1; off < 8; off <<= 1) {
#pragma unroll
    for (int q = 0; q < 16; ++q) acc2[q] += __shfl_xor(acc2[q], off);
  }
#pragma unroll
  for (int q = 0; q < 16; ++q) acc2[q] += fb2[q];
  float gw[32];
#pragma unroll
  for (int k = 0; k < 32; ++k) {
    float s = gbt[k];
#pragma unroll
    for (int q = 0; q < 16; ++q) s = fmaf(acc2[q], gwt[q * 32 + k], s);
    gw[k] = s;
  }
  float v[16];
  float mean = 0.f;
#pragma unroll
  for (int q = 0; q < 16; ++q) {
    float sg = 1.f / (1.f + __expf(-gw[16 + q]));
    v[q] = fmaf(gw[q], sg, xr[q]);
    mean += v[q];
  }
  mean *= (1.f / 16.f);
  float var = 0.f;
#pragma unroll
  for (int q = 0; q < 16; ++q) { float d = v[q] - mean; var = fmaf(d, d, var); }
  var *= (1.f / 16.f);
  float rstd = rsqrtf(var + 1e-5f);
  float mx = -1e30f;
#pragma unroll
  for (int q = 0; q < 16; ++q) {
    v[q] = (v[q] - mean) * rstd * lng[q] + lnb[q];
    mx = fmaxf(mx, v[q]);
  }
  float se = 0.f;
#pragma unroll
  for (int q = 0; q < 16; ++q) { v[q] = __expf(v[q] - mx); se += v[q]; }
  float inv = 1.f / se;
  if (sub == 0) {
#pragma unroll
    for (int i = 0; i < 4; ++i) {
      float4 o = { v[i*4+0]*inv, v[i*4+1]*inv, v[i*4+2]*inv, v[i*4+3]*inv };
      *(float4*)(wout + (size_t)bt * 16 + i * 4) = o;
    }
  }
}

// ---------------------------------------------------------------------------
// G12 (fused g1+g2, validated round 15): y2 = (elu(h0 @ fc1^T + b1') @ fc2^T
// + b2), h0 on the fly, y1 LDS-resident. BM=64, 512 thr (8 waves x 32 cols).
// ---------------------------------------------------------------------------
__global__ __launch_bounds__(512, 2) void g12_kernel(
    const float* __restrict__ x, const float* __restrict__ w1,
    const float* __restrict__ b1, const unsigned short* __restrict__ fc1t,
    const float* __restrict__ fc1_b, const unsigned short* __restrict__ fc2t,
    const float* __restrict__ fc2_b, unsigned short* __restrict__ y2) {
  __shared__ __align__(16) unsigned short hbuf[64 * 264];  // 33792 B
  __shared__ __align__(16) unsigned short bstg[256 * 64];  // 32768 B
  __shared__ float xw[64];
  const int tid = threadIdx.x, lane = tid & 63, wid = tid >> 6;
  const int rl = lane & 15, kc = lane >> 4;
  int hb = blockIdx.x + 128 * blockIdx.y;
  int L  = (hb & 7) * 256 + (hb >> 3);
  const int f = L >> 7, m0 = (L & 127) * 64;
  const unsigned short* B1 = fc1t + (size_t)f * NH * ND;  // [256][256]
  const unsigned short* B2 = fc2t + (size_t)f * ND * NH;  // [256][256]
  const float* w1f = w1 + f * ND;
  const float* b1f = b1 + f * ND;
  const int wn = wid * 32;

  if (tid < 64) xw[tid] = x[(size_t)(m0 + tid) * NF + f];
  __syncthreads();

#pragma unroll
  for (int i = 0; i < 4; ++i) {
    int j = tid + 512 * i;
    int row = j >> 5, c = (j & 31) * 8;
    float xv = xw[row];
    float4 wa = *(const float4*)(w1f + c);
    float4 wb = *(const float4*)(w1f + c + 4);
    float4 ba = *(const float4*)(b1f + c);
    float4 bb = *(const float4*)(b1f + c + 4);
    u16x8 o;
    o[0] = f2bf(fmaxf(fmaf(xv, wa.x, ba.x), 0.f));
    o[1] = f2bf(fmaxf(fmaf(xv, wa.y, ba.y), 0.f));
    o[2] = f2bf(fmaxf(fmaf(xv, wa.z, ba.z), 0.f));
    o[3] = f2bf(fmaxf(fmaf(xv, wa.w, ba.w), 0.f));
    o[4] = f2bf(fmaxf(fmaf(xv, wb.x, bb.x), 0.f));
    o[5] = f2bf(fmaxf(fmaf(xv, wb.y, bb.y), 0.f));
    o[6] = f2bf(fmaxf(fmaf(xv, wb.z, bb.z), 0.f));
    o[7] = f2bf(fmaxf(fmaf(xv, wb.w, bb.w), 0.f));
    *(u16x8*)(hbuf + row * 264 + c) = o;
  }
  __syncthreads();

  f32x4 acc[4][2];
#pragma unroll
  for (int m = 0; m < 4; ++m)
#pragma unroll
    for (int n = 0; n < 2; ++n) acc[m][n] = (f32x4){0.f, 0.f, 0.f, 0.f};

  for (int kt = 0; kt < ND; kt += 64) {
    if (kt) __syncthreads();
#pragma unroll
    for (int i = 0; i < 4; ++i) {
      int s = tid + 512 * i;
      int row = s >> 3, sl = s & 7;
      GLOAD16(B1 + (size_t)row * ND + kt + ((sl ^ (row & 7)) << 3),
              (char*)bstg + (wid * 64 + 512 * i) * 16);
    }
    __syncthreads();
#pragma unroll
    for (int kk = 0; kk < 2; ++kk) {
      int s = kk * 4 + kc;
      bf16x8 av[4], bv[2];
#pragma unroll
      for (int n = 0; n < 2; ++n) {
        int rr = wn + n * 16 + rl;
        int ps = s ^ (rr & 7);
        bv[n] = *(const bf16x8*)((const char*)bstg + rr * 128 + ps * 16);
      }
#pragma unroll
      for (int m = 0; m < 4; ++m)
        av[m] = *(const bf16x8*)(hbuf + (m * 16 + rl) * 264 + kt + s * 8);
#pragma unroll
      for (int m = 0; m < 4; ++m)
#pragma unroll
        for (int n = 0; n < 2; ++n)
          acc[m][n] = __builtin_amdgcn_mfma_f32_16x16x32_bf16(av[m], bv[n],
                                                              acc[m][n], 0, 0, 0);
    }
  }
  __syncthreads();

#pragma unroll
  for (int n = 0; n < 2; ++n) {
    int c = wn + n * 16 + rl;
    float bvv = fc1_b[f * NH + c];
#pragma unroll
    for (int m = 0; m < 4; ++m) {
#pragma unroll
      for (int j = 0; j < 4; ++j) {
        int r = m * 16 + kc * 4 + j;
        float v = acc[m][n][j] + bvv;
        v = v > 0.f ? v : expm1f(v);
        hbuf[r * 264 + c] = f2bf(v);
      }
    }
  }
  __syncthreads();

#pragma unroll
  for (int m = 0; m < 4; ++m)
#pragma unroll
    for (int n = 0; n < 2; ++n) acc[m][n] = (f32x4){0.f, 0.f, 0.f, 0.f};

  for (int kt = 0; kt < NH; kt += 64) {
    if (kt) __syncthreads();
#pragma unroll
    for (int i = 0; i < 4; ++i) {
      int s = tid + 512 * i;
      int row = s >> 3, sl = s & 7;
      GLOAD16(B2 + (size_t)row * NH + kt + ((sl ^ (row & 7)) << 3),
              (char*)bstg + (wid * 64 + 512 * i) * 16);
    }
    __syncthreads();
#pragma unroll
    for (int kk = 0; kk < 2; ++kk) {
      int s = kk * 4 + kc;
      bf16x8 av[4], bv[2];
#pragma unroll
      for (int n = 0; n < 2; ++n) {
        int rr = wn + n * 16 + rl;
        int ps = s ^ (rr & 7);
        bv[n] = *(const bf16x8*)((const char*)bstg + rr * 128 + ps * 16);
      }
#pragma unroll
      for (int m = 0; m < 4; ++m)
        av[m] = *(const bf16x8*)(hbuf + (m * 16 + rl) * 264 + kt + s * 8);
#pragma unroll
      for (int m = 0; m < 4; ++m)
#pragma unroll
        for (int n = 0; n < 2; ++n)
          acc[m][n] = __builtin_amdgcn_mfma_f32_16x16x32_bf16(av[m], bv[n],
                                                              acc[m][n], 0, 0, 0);
    }
  }
  __syncthreads();

#pragma unroll
  for (int n = 0; n < 2; ++n) {
    int c = wn + n * 16 + rl;
    float bvv = fc2_b[f * ND + c];
#pragma unroll
    for (int m = 0; m < 4; ++m) {
#pragma unroll
      for (int j = 0; j < 4; ++j) {
        int r = m * 16 + kc * 4 + j;
        hbuf[r * 264 + c] = f2bf(acc[m][n][j] + bvv);
      }
    }
  }
  __syncthreads();
#pragma unroll
  for (int v = 0; v < 4; ++v) {
    int job = tid + 512 * v;
    int row = job >> 5, ch = job & 31;
    u16x8 val = *(const u16x8*)(hbuf + row * 264 + ch * 8);
    *(u16x8*)(y2 + ((size_t)f * NBT + m0 + row) * ND + ch * 8) = val;
  }
}

// ---------------------------------------------------------------------------
// G3 (round-11/15 verbatim): a|gate = y2 @ glu^T + b; v = h0 + a*sig(gate);
// LN -> H. BM=64, BN=512(=N), BK=64, 512 thr.
// ---------------------------------------------------------------------------
__global__ __launch_bounds__(512, 4) void g3_kernel(
    const unsigned short* __restrict__ y2,
    const unsigned short* __restrict__ glut, const float* __restrict__ glu_b,
    const float* __restrict__ x, const float* __restrict__ w1,
    const float* __restrict__ b1, const float* __restrict__ ln_g,
    const float* __restrict__ ln_b, unsigned short* __restrict__ H) {
  __shared__ __align__(16) char arena[73728];  // A 8K + B 64K | vbuf 33792
  __shared__ float xw[64];
  __shared__ float2 sums[8][64];
  __shared__ float2 sums2[64];
  unsigned short* abuf = (unsigned short*)arena;            // [64][64]
  unsigned short* bbuf = (unsigned short*)(arena + 8192);   // [512][64]
  unsigned short* vbuf = (unsigned short*)arena;            // [64][264]

  const int tid = threadIdx.x, lane = tid & 63, wid = tid >> 6;
  const int rl = lane & 15, rq = lane >> 4;
  int hb = blockIdx.x + 128 * blockIdx.y;
  int L  = (hb & 7) * 256 + (hb >> 3);
  const int f = L >> 7, m0 = (L & 127) * 64;
  const unsigned short* Af = y2 + (size_t)f * NBT * ND;
  const unsigned short* Bf = glut + (size_t)f * ND * N2D;  // [512][256]
  const float* w1f = w1 + f * ND;
  const float* b1f = b1 + f * ND;
  const int colb = wid * 32;
  if (tid < 64) xw[tid] = x[(size_t)(m0 + tid) * NF + f];

  f32x4 acc[4][4];
#pragma unroll
  for (int m = 0; m < 4; ++m)
#pragma unroll
    for (int n = 0; n < 4; ++n) acc[m][n] = (f32x4){0.f, 0.f, 0.f, 0.f};

  for (int kt = 0; kt < ND; kt += 64) {
    __syncthreads();
    {  // A [64][64]
      int s = tid;
      int row = s >> 3, sl = s & 7;
      const unsigned short* ga =
          Af + (size_t)(m0 + row) * ND + kt + ((sl ^ (row & 7)) << 3);
      GLOAD16(ga, (char*)abuf + (wid * 64) * 16);
    }
#pragma unroll
    for (int i = 0; i < 8; ++i) {  // B [512][64]
      int s = tid + 512 * i;
      int row = s >> 3, sl = s & 7;
      const unsigned short* gb =
          Bf + (size_t)row * ND + kt + ((sl ^ (row & 7)) << 3);
      GLOAD16(gb, (char*)bbuf + (wid * 64 + 512 * i) * 16);
    }
    __syncthreads();
#pragma unroll
    for (int kk = 0; kk < 2; ++kk) {
      bf16x8 av[4], bv[4];
      int s = kk * 4 + rq;
#pragma unroll
      for (int m = 0; m < 4; ++m) {
        int r = m * 16 + rl;
        int ps = s ^ (r & 7);
        av[m] = *(const bf16x8*)((const char*)abuf + r * 128 + ps * 16);
      }
#pragma unroll
      for (int n = 0; n < 4; ++n) {
        int rr = (n < 2) ? (colb + n * 16 + rl)
                         : (256 + colb + (n - 2) * 16 + rl);
        int ps = s ^ (rr & 7);
        bv[n] = *(const bf16x8*)((const char*)bbuf + rr * 128 + ps * 16);
      }
#pragma unroll
      for (int m = 0; m < 4; ++m)
#pragma unroll
        for (int n = 0; n < 4; ++n)
          acc[m][n] = __builtin_amdgcn_mfma_f32_16x16x32_bf16(av[m], bv[n],
                                                              acc[m][n], 0, 0, 0);
    }
  }

#pragma unroll
  for (int n = 0; n < 2; ++n) {
    int cA = colb + n * 16 + rl;
    float ab_ = glu_b[f * N2D + cA];
    float gb_ = glu_b[f * N2D + 256 + cA];
    float w1c = w1f[cA], b1c = b1f[cA];
#pragma unroll
    for (int m = 0; m < 4; ++m) {
#pragma unroll
      for (int j = 0; j < 4; ++j) {
        int r = m * 16 + rq * 4 + j;
        float a = acc[m][n][j] + ab_;
        float g = acc[m][n + 2][j] + gb_;
        float sg = 1.f / (1.f + __expf(-g));
        float h0 = fmaxf(fmaf(xw[r], w1c, b1c), 0.f);
        acc[m][n][j] = fmaf(a, sg, h0);
      }
    }
  }
#pragma unroll
  for (int m = 0; m < 4; ++m) {
#pragma unroll
    for (int j = 0; j < 4; ++j) {
      float s = acc[m][0][j] + acc[m][1][j];
      float q = fmaf(acc[m][0][j], acc[m][0][j],
                     acc[m][1][j] * acc[m][1][j]);
#pragma unroll
      for (int off = 1; off < 16; off <<= 1) {
        s += __shfl_xor(s, off);
        q += __shfl_xor(q, off);
      }
      if (rl == 0) sums[wid][m * 16 + rq * 4 + j] = make_float2(s, q);
    }
  }
  __syncthreads();
  if (tid < 64) {
    float tot = 0.f, tot2 = 0.f;
#pragma unroll
    for (int wv = 0; wv < 8; ++wv) {
      float2 p = sums[wv][tid];
      tot += p.x;
      tot2 += p.y;
    }
    float mean = tot * (1.f / 256.f);
    float var  = tot2 * (1.f / 256.f) - mean * mean;
    sums2[tid] = make_float2(mean, rsqrtf(var + 1e-5f));
  }
  __syncthreads();
#pragma unroll
  for (int n = 0; n < 2; ++n) {
    int cA = colb + n * 16 + rl;
    float lg = ln_g[f * ND + cA], lb = ln_b[f * ND + cA];
#pragma unroll
    for (int m = 0; m < 4; ++m) {
#pragma unroll
      for (int j = 0; j < 4; ++j) {
        int r = m * 16 + rq * 4 + j;
        float2 mr = sums2[r];
        vbuf[r * 264 + cA] = f2bf(fmaf((acc[m][n][j] - mr.x) * mr.y, lg, lb));
      }
    }
  }
  __syncthreads();
  {
    int row = tid >> 3, chunk = tid & 7;
    unsigned short* Hrow = H + ((size_t)f * NBT + m0 + row) * ND;
#pragma unroll
    for (int v = 0; v < 4; ++v) {
      u16x8 val = *(const u16x8*)(vbuf + row * 264 + chunk * 8 + v * 64);
      *(u16x8*)(Hrow + chunk * 8 + v * 64) = val;
    }
  }
}

// ---------------------------------------------------------------------------
// z[bt][d] = sum_f H[f][bt][d] * w[bt][f]  (validated round 1)
// ---------------------------------------------------------------------------
__global__ __launch_bounds__(256) void combine_kernel(
    const unsigned short* __restrict__ H, const float* __restrict__ w,
    float* __restrict__ z) {
  int idx = blockIdx.x * 256 + threadIdx.x;
  int bt = idx >> 5;
  int d  = (idx & 31) << 3;
  float a[8];
#pragma unroll
  for (int j = 0; j < 8; ++j) a[j] = 0.f;
#pragma unroll
  for (int f = 0; f < 16; ++f) {
    u16x8 hv = *(const u16x8*)(H + ((size_t)f * NBT + bt) * ND + d);
    float wvv = w[bt * 16 + f];
#pragma unroll
    for (int j = 0; j < 8; ++j) a[j] = fmaf(bf2f(hv[j]), wvv, a[j]);
  }
  float4 o0 = {a[0], a[1], a[2], a[3]};
  float4 o1 = {a[4], a[5], a[6], a[7]};
  *(float4*)(z + (size_t)bt * ND + d)     = o0;
  *(float4*)(z + (size_t)bt * ND + d + 4) = o1;
}

// ---------------------------------------------------------------------------
extern "C" void kernel_launch(void* const* d_in, const int* in_sizes, int n_in,
                              void* d_out, int out_size, void* d_ws,
                              size_t ws_size, hipStream_t stream) {
  const float* x        = (const float*)d_in[0];
  const float* w1       = (const float*)d_in[1];
  const float* b1       = (const float*)d_in[2];
  const float* fc1_w    = (const float*)d_in[3];
  const float* fc1_b    = (const float*)d_in[4];
  const float* fc2_w    = (const float*)d_in[5];
  const float* fc2_b    = (const float*)d_in[6];
  const float* glu_w    = (const float*)d_in[7];
  const float* glu_b    = (const float*)d_in[8];
  const float* ln_g     = (const float*)d_in[9];
  const float* ln_b     = (const float*)d_in[10];
  const float* wg_fc1_w = (const float*)d_in[11];
  const float* wg_fc1_b = (const float*)d_in[12];
  const float* wg_fc2_w = (const float*)d_in[13];
  const float* wg_fc2_b = (const float*)d_in[14];
  const float* wg_glu_w = (const float*)d_in[15];
  const float* wg_glu_b = (const float*)d_in[16];
  const float* wg_ln_g  = (const float*)d_in[17];
  const float* wg_ln_b  = (const float*)d_in[18];

  char* ws = (char*)d_ws;
  unsigned short* fc1t = (unsigned short*)ws;                       // 2 MB
  unsigned short* fc2t = fc1t + (size_t)NF * NH * ND;               // 2 MB
  unsigned short* glut = fc2t + (size_t)NF * ND * NH;               // 4 MB
  unsigned short* y2   = (unsigned short*)(ws + (8ull << 20));      // 64 MiB
  unsigned short* Hbuf = (unsigned short*)(ws + (72ull << 20));     // 64 MiB

  float* zout = (float*)d_out;                 // [NBT][ND]
  float* wout = zout + (size_t)NBT * ND;       // [NBT][16]

  prep_kernel<<<dim3(16, 8, 66), 256, 0, stream>>>(
      fc1_w, fc2_w, glu_w, fc1t, fc2t, glut, x, wg_fc1_w, wg_fc1_b, wg_fc2_w,
      wg_fc2_b, wg_glu_w, wg_glu_b, wg_ln_g, wg_ln_b, wout);

  g12_kernel<<<dim3(128, 16), 512, 0, stream>>>(x, w1, b1, fc1t, fc1_b, fc2t,
                                                fc2_b, y2);
  g3_kernel<<<dim3(128, 16), 512, 0, stream>>>(y2, glut, glu_b, x, w1, b1,
                                               ln_g, ln_b, Hbuf);
  combine_kernel<<<(NBT * ND / 8) / 256, 256, 0, stream>>>(Hbuf, wout, zout);

  (void)in_sizes; (void)n_in; (void)out_size; (void)ws_size;
}

// Round 19
// 194.923 us; speedup vs baseline: 1.0262x; 1.0262x over previous
//
#include <hip/hip_runtime.h>
#include <hip/hip_bf16.h>

#define NBT 8192      // B*T
#define NF  16
#define ND  256
#define NH  256
#define N2D 512

typedef short bf16x8 __attribute__((ext_vector_type(8)));
typedef float f32x4 __attribute__((ext_vector_type(4)));
typedef unsigned short u16x8 __attribute__((ext_vector_type(8)));

__device__ __forceinline__ float bf2f(unsigned short u) {
  return __uint_as_float(((unsigned)u) << 16);
}
__device__ __forceinline__ unsigned short f2bf(float f) {
  unsigned u = __float_as_uint(f);
  return (unsigned short)((u + 0x7FFFu + ((u >> 16) & 1u)) >> 16);
}

#define GLOAD16(src, dst)                                                     \
  __builtin_amdgcn_global_load_lds(                                           \
      (const __attribute__((address_space(1))) unsigned int*)(src),           \
      (__attribute__((address_space(3))) unsigned int*)(dst), 16, 0, 0)

// ---------------------------------------------------------------------------
// Weight GRN + softmax -> w [NBT][16] (fp32 exact; validated round 1)
// ---------------------------------------------------------------------------
__global__ __launch_bounds__(256) void wgrn_kernel(
    const float* __restrict__ x, const float* __restrict__ fw1,
    const float* __restrict__ fb1, const float* __restrict__ fw2,
    const float* __restrict__ fb2, const float* __restrict__ gwt,
    const float* __restrict__ gbt, const float* __restrict__ lng,
    const float* __restrict__ lnb, float* __restrict__ wout) {
  __shared__ float w1t[256 * 16];
  __shared__ float w2s[256 * 16];
  const int tid = threadIdx.x;
  for (int i = tid; i < 4096; i += 256) {
    int ff = i >> 8, j = i & 255;
    w1t[j * 16 + ff] = fw1[i];
    w2s[i] = fw2[i];
  }
  __syncthreads();
  const int sub  = tid & 7;
  const int rowi = tid >> 3;
  const int bt   = blockIdx.x * 32 + rowi;
  float xr[16];
#pragma unroll
  for (int i = 0; i < 4; ++i)
    *(float4*)&xr[i * 4] = *(const float4*)(x + (size_t)bt * 16 + i * 4);
  float acc2[16];
#pragma unroll
  for (int q = 0; q < 16; ++q) acc2[q] = 0.f;
  for (int j = sub; j < 256; j += 8) {
    float h = fb1[j];
    const float* wr = &w1t[j * 16];
#pragma unroll
    for (int q = 0; q < 16; ++q) h = fmaf(xr[q], wr[q], h);
    h = h > 0.f ? h : expm1f(h);
    const float* w2r = &w2s[j * 16];
#pragma unroll
    for (int q = 0; q < 16; ++q) acc2[q] = fmaf(h, w2r[q], acc2[q]);
  }
#pragma unroll
  for (int off = 1; off < 8; off <<= 1) {
#pragma unroll
    for (int q = 0; q < 16; ++q) acc2[q] += __shfl_xor(acc2[q], off);
  }
#pragma unroll
  for (int q = 0; q < 16; ++q) acc2[q] += fb2[q];
  float gw[32];
#pragma unroll
  for (int k = 0; k < 32; ++k) {
    float s = gbt[k];
#pragma unroll
    for (int q = 0; q < 16; ++q) s = fmaf(acc2[q], gwt[q * 32 + k], s);
    gw[k] = s;
  }
  float v[16];
  float mean = 0.f;
#pragma unroll
  for (int q = 0; q < 16; ++q) {
    float sg = 1.f / (1.f + __expf(-gw[16 + q]));
    v[q] = fmaf(gw[q], sg, xr[q]);
    mean += v[q];
  }
  mean *= (1.f / 16.f);
  float var = 0.f;
#pragma unroll
  for (int q = 0; q < 16; ++q) { float d = v[q] - mean; var = fmaf(d, d, var); }
  var *= (1.f / 16.f);
  float rstd = rsqrtf(var + 1e-5f);
  float mx = -1e30f;
#pragma unroll
  for (int q = 0; q < 16; ++q) {
    v[q] = (v[q] - mean) * rstd * lng[q] + lnb[q];
    mx = fmaxf(mx, v[q]);
  }
  float se = 0.f;
#pragma unroll
  for (int q = 0; q < 16; ++q) { v[q] = __expf(v[q] - mx); se += v[q]; }
  float inv = 1.f / se;
  if (sub == 0) {
#pragma unroll
    for (int i = 0; i < 4; ++i) {
      float4 o = { v[i*4+0]*inv, v[i*4+1]*inv, v[i*4+2]*inv, v[i*4+3]*inv };
      *(float4*)(wout + (size_t)bt * 16 + i * 4) = o;
    }
  }
}

// ---------------------------------------------------------------------------
// Fused weight prep: fp32 [K][N] -> bf16 [N][K] (validated rounds 5-17)
// ---------------------------------------------------------------------------
__global__ void transpose_all(const float* __restrict__ fc1_w,
                              const float* __restrict__ fc2_w,
                              const float* __restrict__ glu_w,
                              unsigned short* __restrict__ fc1t,
                              unsigned short* __restrict__ fc2t,
                              unsigned short* __restrict__ glut) {
  __shared__ float tile[32][33];
  const int which = blockIdx.z >> 4;
  const int f     = blockIdx.z & 15;
  const float* src;
  unsigned short* dst;
  int K, N, bx = blockIdx.x;
  if (which == 0)      { src = fc1_w; dst = fc1t; K = ND; N = NH; }
  else if (which == 1) { src = fc2_w; dst = fc2t; K = NH; N = ND; }
  else                 { src = glu_w; dst = glut; K = ND; N = N2D;
                         bx += (which == 3) ? 8 : 0; }
  if (bx * 32 >= N) return;
  const float* s = src + (size_t)f * K * N;
  unsigned short* d = dst + (size_t)f * K * N;
  const int k0 = blockIdx.y * 32, n0 = bx * 32;
  const int tx = threadIdx.x, ty = threadIdx.y;
#pragma unroll
  for (int i = 0; i < 32; i += 8)
    tile[ty + i][tx] = s[(size_t)(k0 + ty + i) * N + n0 + tx];
  __syncthreads();
#pragma unroll
  for (int i = 0; i < 32; i += 8)
    d[(size_t)(n0 + ty + i) * K + k0 + tx] = f2bf(tile[tx][ty + i]);
}

// ---------------------------------------------------------------------------
// G12 (fused g1+g2, validated round 15; launch_bounds (512,4) = 2 blocks/CU
// per G1 semantics: w=4 waves/EU * 4 EU / 8 waves-per-block = 2).
// y2 = (elu(h0 @ fc1^T + b1') @ fc2^T + b2), h0 on the fly, y1 LDS-resident.
// ---------------------------------------------------------------------------
__global__ __launch_bounds__(512, 4) void g12_kernel(
    const float* __restrict__ x, const float* __restrict__ w1,
    const float* __restrict__ b1, const unsigned short* __restrict__ fc1t,
    const float* __restrict__ fc1_b, const unsigned short* __restrict__ fc2t,
    const float* __restrict__ fc2_b, unsigned short* __restrict__ y2) {
  __shared__ __align__(16) unsigned short hbuf[64 * 264];  // 33792 B
  __shared__ __align__(16) unsigned short bstg[256 * 64];  // 32768 B
  __shared__ float xw[64];
  const int tid = threadIdx.x, lane = tid & 63, wid = tid >> 6;
  const int rl = lane & 15, kc = lane >> 4;
  int hb = blockIdx.x + 128 * blockIdx.y;
  int L  = (hb & 7) * 256 + (hb >> 3);
  const int f = L >> 7, m0 = (L & 127) * 64;
  const unsigned short* B1 = fc1t + (size_t)f * NH * ND;  // [256][256]
  const unsigned short* B2 = fc2t + (size_t)f * ND * NH;  // [256][256]
  const float* w1f = w1 + f * ND;
  const float* b1f = b1 + f * ND;
  const int wn = wid * 32;

  if (tid < 64) xw[tid] = x[(size_t)(m0 + tid) * NF + f];
  __syncthreads();

#pragma unroll
  for (int i = 0; i < 4; ++i) {
    int j = tid + 512 * i;
    int row = j >> 5, c = (j & 31) * 8;
    float xv = xw[row];
    float4 wa = *(const float4*)(w1f + c);
    float4 wb = *(const float4*)(w1f + c + 4);
    float4 ba = *(const float4*)(b1f + c);
    float4 bb = *(const float4*)(b1f + c + 4);
    u16x8 o;
    o[0] = f2bf(fmaxf(fmaf(xv, wa.x, ba.x), 0.f));
    o[1] = f2bf(fmaxf(fmaf(xv, wa.y, ba.y), 0.f));
    o[2] = f2bf(fmaxf(fmaf(xv, wa.z, ba.z), 0.f));
    o[3] = f2bf(fmaxf(fmaf(xv, wa.w, ba.w), 0.f));
    o[4] = f2bf(fmaxf(fmaf(xv, wb.x, bb.x), 0.f));
    o[5] = f2bf(fmaxf(fmaf(xv, wb.y, bb.y), 0.f));
    o[6] = f2bf(fmaxf(fmaf(xv, wb.z, bb.z), 0.f));
    o[7] = f2bf(fmaxf(fmaf(xv, wb.w, bb.w), 0.f));
    *(u16x8*)(hbuf + row * 264 + c) = o;
  }
  __syncthreads();

  f32x4 acc[4][2];
#pragma unroll
  for (int m = 0; m < 4; ++m)
#pragma unroll
    for (int n = 0; n < 2; ++n) acc[m][n] = (f32x4){0.f, 0.f, 0.f, 0.f};

  for (int kt = 0; kt < ND; kt += 64) {
    if (kt) __syncthreads();
#pragma unroll
    for (int i = 0; i < 4; ++i) {
      int s = tid + 512 * i;
      int row = s >> 3, sl = s & 7;
      GLOAD16(B1 + (size_t)row * ND + kt + ((sl ^ (row & 7)) << 3),
              (char*)bstg + (wid * 64 + 512 * i) * 16);
    }
    __syncthreads();
#pragma unroll
    for (int kk = 0; kk < 2; ++kk) {
      int s = kk * 4 + kc;
      bf16x8 av[4], bv[2];
#pragma unroll
      for (int n = 0; n < 2; ++n) {
        int rr = wn + n * 16 + rl;
        int ps = s ^ (rr & 7);
        bv[n] = *(const bf16x8*)((const char*)bstg + rr * 128 + ps * 16);
      }
#pragma unroll
      for (int m = 0; m < 4; ++m)
        av[m] = *(const bf16x8*)(hbuf + (m * 16 + rl) * 264 + kt + s * 8);
#pragma unroll
      for (int m = 0; m < 4; ++m)
#pragma unroll
        for (int n = 0; n < 2; ++n)
          acc[m][n] = __builtin_amdgcn_mfma_f32_16x16x32_bf16(av[m], bv[n],
                                                              acc[m][n], 0, 0, 0);
    }
  }
  __syncthreads();

#pragma unroll
  for (int n = 0; n < 2; ++n) {
    int c = wn + n * 16 + rl;
    float bvv = fc1_b[f * NH + c];
#pragma unroll
    for (int m = 0; m < 4; ++m) {
#pragma unroll
      for (int j = 0; j < 4; ++j) {
        int r = m * 16 + kc * 4 + j;
        float v = acc[m][n][j] + bvv;
        v = v > 0.f ? v : expm1f(v);
        hbuf[r * 264 + c] = f2bf(v);
      }
    }
  }
  __syncthreads();

#pragma unroll
  for (int m = 0; m < 4; ++m)
#pragma unroll
    for (int n = 0; n < 2; ++n) acc[m][n] = (f32x4){0.f, 0.f, 0.f, 0.f};

  for (int kt = 0; kt < NH; kt += 64) {
    if (kt) __syncthreads();
#pragma unroll
    for (int i = 0; i < 4; ++i) {
      int s = tid + 512 * i;
      int row = s >> 3, sl = s & 7;
      GLOAD16(B2 + (size_t)row * NH + kt + ((sl ^ (row & 7)) << 3),
              (char*)bstg + (wid * 64 + 512 * i) * 16);
    }
    __syncthreads();
#pragma unroll
    for (int kk = 0; kk < 2; ++kk) {
      int s = kk * 4 + kc;
      bf16x8 av[4], bv[2];
#pragma unroll
      for (int n = 0; n < 2; ++n) {
        int rr = wn + n * 16 + rl;
        int ps = s ^ (rr & 7);
        bv[n] = *(const bf16x8*)((const char*)bstg + rr * 128 + ps * 16);
      }
#pragma unroll
      for (int m = 0; m < 4; ++m)
        av[m] = *(const bf16x8*)(hbuf + (m * 16 + rl) * 264 + kt + s * 8);
#pragma unroll
      for (int m = 0; m < 4; ++m)
#pragma unroll
        for (int n = 0; n < 2; ++n)
          acc[m][n] = __builtin_amdgcn_mfma_f32_16x16x32_bf16(av[m], bv[n],
                                                              acc[m][n], 0, 0, 0);
    }
  }
  __syncthreads();

#pragma unroll
  for (int n = 0; n < 2; ++n) {
    int c = wn + n * 16 + rl;
    float bvv = fc2_b[f * ND + c];
#pragma unroll
    for (int m = 0; m < 4; ++m) {
#pragma unroll
      for (int j = 0; j < 4; ++j) {
        int r = m * 16 + kc * 4 + j;
        hbuf[r * 264 + c] = f2bf(acc[m][n][j] + bvv);
      }
    }
  }
  __syncthreads();
#pragma unroll
  for (int v = 0; v < 4; ++v) {
    int job = tid + 512 * v;
    int row = job >> 5, ch = job & 31;
    u16x8 val = *(const u16x8*)(hbuf + row * 264 + ch * 8);
    *(u16x8*)(y2 + ((size_t)f * NBT + m0 + row) * ND + ch * 8) = val;
  }
}

// ---------------------------------------------------------------------------
// G3 (round-11/15 verbatim): a|gate = y2 @ glu^T + b; v = h0 + a*sig(gate);
// LN -> H. BM=64, BN=512(=N), BK=64, 512 thr.
// ---------------------------------------------------------------------------
__global__ __launch_bounds__(512, 4) void g3_kernel(
    const unsigned short* __restrict__ y2,
    const unsigned short* __restrict__ glut, const float* __restrict__ glu_b,
    const float* __restrict__ x, const float* __restrict__ w1,
    const float* __restrict__ b1, const float* __restrict__ ln_g,
    const float* __restrict__ ln_b, unsigned short* __restrict__ H) {
  __shared__ __align__(16) char arena[73728];  // A 8K + B 64K | vbuf 33792
  __shared__ float xw[64];
  __shared__ float2 sums[8][64];
  __shared__ float2 sums2[64];
  unsigned short* abuf = (unsigned short*)arena;            // [64][64]
  unsigned short* bbuf = (unsigned short*)(arena + 8192);   // [512][64]
  unsigned short* vbuf = (unsigned short*)arena;            // [64][264]

  const int tid = threadIdx.x, lane = tid & 63, wid = tid >> 6;
  const int rl = lane & 15, rq = lane >> 4;
  int hb = blockIdx.x + 128 * blockIdx.y;
  int L  = (hb & 7) * 256 + (hb >> 3);
  const int f = L >> 7, m0 = (L & 127) * 64;
  const unsigned short* Af = y2 + (size_t)f * NBT * ND;
  const unsigned short* Bf = glut + (size_t)f * ND * N2D;  // [512][256]
  const float* w1f = w1 + f * ND;
  const float* b1f = b1 + f * ND;
  const int colb = wid * 32;
  if (tid < 64) xw[tid] = x[(size_t)(m0 + tid) * NF + f];

  f32x4 acc[4][4];
#pragma unroll
  for (int m = 0; m < 4; ++m)
#pragma unroll
    for (int n = 0; n < 4; ++n) acc[m][n] = (f32x4){0.f, 0.f, 0.f, 0.f};

  for (int kt = 0; kt < ND; kt += 64) {
    __syncthreads();
    {  // A [64][64]
      int s = tid;
      int row = s >> 3, sl = s & 7;
      const unsigned short* ga =
          Af + (size_t)(m0 + row) * ND + kt + ((sl ^ (row & 7)) << 3);
      GLOAD16(ga, (char*)abuf + (wid * 64) * 16);
    }
#pragma unroll
    for (int i = 0; i < 8; ++i) {  // B [512][64]
      int s = tid + 512 * i;
      int row = s >> 3, sl = s & 7;
      const unsigned short* gb =
          Bf + (size_t)row * ND + kt + ((sl ^ (row & 7)) << 3);
      GLOAD16(gb, (char*)bbuf + (wid * 64 + 512 * i) * 16);
    }
    __syncthreads();
#pragma unroll
    for (int kk = 0; kk < 2; ++kk) {
      bf16x8 av[4], bv[4];
      int s = kk * 4 + rq;
#pragma unroll
      for (int m = 0; m < 4; ++m) {
        int r = m * 16 + rl;
        int ps = s ^ (r & 7);
        av[m] = *(const bf16x8*)((const char*)abuf + r * 128 + ps * 16);
      }
#pragma unroll
      for (int n = 0; n < 4; ++n) {
        int rr = (n < 2) ? (colb + n * 16 + rl)
                         : (256 + colb + (n - 2) * 16 + rl);
        int ps = s ^ (rr & 7);
        bv[n] = *(const bf16x8*)((const char*)bbuf + rr * 128 + ps * 16);
      }
#pragma unroll
      for (int m = 0; m < 4; ++m)
#pragma unroll
        for (int n = 0; n < 4; ++n)
          acc[m][n] = __builtin_amdgcn_mfma_f32_16x16x32_bf16(av[m], bv[n],
                                                              acc[m][n], 0, 0, 0);
    }
  }

#pragma unroll
  for (int n = 0; n < 2; ++n) {
    int cA = colb + n * 16 + rl;
    float ab_ = glu_b[f * N2D + cA];
    float gb_ = glu_b[f * N2D + 256 + cA];
    float w1c = w1f[cA], b1c = b1f[cA];
#pragma unroll
    for (int m = 0; m < 4; ++m) {
#pragma unroll
      for (int j = 0; j < 4; ++j) {
        int r = m * 16 + rq * 4 + j;
        float a = acc[m][n][j] + ab_;
        float g = acc[m][n + 2][j] + gb_;
        float sg = 1.f / (1.f + __expf(-g));
        float h0 = fmaxf(fmaf(xw[r], w1c, b1c), 0.f);
        acc[m][n][j] = fmaf(a, sg, h0);
      }
    }
  }
#pragma unroll
  for (int m = 0; m < 4; ++m) {
#pragma unroll
    for (int j = 0; j < 4; ++j) {
      float s = acc[m][0][j] + acc[m][1][j];
      float q = fmaf(acc[m][0][j], acc[m][0][j],
                     acc[m][1][j] * acc[m][1][j]);
#pragma unroll
      for (int off = 1; off < 16; off <<= 1) {
        s += __shfl_xor(s, off);
        q += __shfl_xor(q, off);
      }
      if (rl == 0) sums[wid][m * 16 + rq * 4 + j] = make_float2(s, q);
    }
  }
  __syncthreads();
  if (tid < 64) {
    float tot = 0.f, tot2 = 0.f;
#pragma unroll
    for (int wv = 0; wv < 8; ++wv) {
      float2 p = sums[wv][tid];
      tot += p.x;
      tot2 += p.y;
    }
    float mean = tot * (1.f / 256.f);
    float var  = tot2 * (1.f / 256.f) - mean * mean;
    sums2[tid] = make_float2(mean, rsqrtf(var + 1e-5f));
  }
  __syncthreads();
#pragma unroll
  for (int n = 0; n < 2; ++n) {
    int cA = colb + n * 16 + rl;
    float lg = ln_g[f * ND + cA], lb = ln_b[f * ND + cA];
#pragma unroll
    for (int m = 0; m < 4; ++m) {
#pragma unroll
      for (int j = 0; j < 4; ++j) {
        int r = m * 16 + rq * 4 + j;
        float2 mr = sums2[r];
        vbuf[r * 264 + cA] = f2bf(fmaf((acc[m][n][j] - mr.x) * mr.y, lg, lb));
      }
    }
  }
  __syncthreads();
  {
    int row = tid >> 3, chunk = tid & 7;
    unsigned short* Hrow = H + ((size_t)f * NBT + m0 + row) * ND;
#pragma unroll
    for (int v = 0; v < 4; ++v) {
      u16x8 val = *(const u16x8*)(vbuf + row * 264 + chunk * 8 + v * 64);
      *(u16x8*)(Hrow + chunk * 8 + v * 64) = val;
    }
  }
}

// ---------------------------------------------------------------------------
// z[bt][d] = sum_f H[f][bt][d] * w[bt][f]  (validated round 1)
// ---------------------------------------------------------------------------
__global__ __launch_bounds__(256) void combine_kernel(
    const unsigned short* __restrict__ H, const float* __restrict__ w,
    float* __restrict__ z) {
  int idx = blockIdx.x * 256 + threadIdx.x;
  int bt = idx >> 5;
  int d  = (idx & 31) << 3;
  float a[8];
#pragma unroll
  for (int j = 0; j < 8; ++j) a[j] = 0.f;
#pragma unroll
  for (int f = 0; f < 16; ++f) {
    u16x8 hv = *(const u16x8*)(H + ((size_t)f * NBT + bt) * ND + d);
    float wvv = w[bt * 16 + f];
#pragma unroll
    for (int j = 0; j < 8; ++j) a[j] = fmaf(bf2f(hv[j]), wvv, a[j]);
  }
  float4 o0 = {a[0], a[1], a[2], a[3]};
  float4 o1 = {a[4], a[5], a[6], a[7]};
  *(float4*)(z + (size_t)bt * ND + d)     = o0;
  *(float4*)(z + (size_t)bt * ND + d + 4) = o1;
}

// ---------------------------------------------------------------------------
extern "C" void kernel_launch(void* const* d_in, const int* in_sizes, int n_in,
                              void* d_out, int out_size, void* d_ws,
                              size_t ws_size, hipStream_t stream) {
  const float* x        = (const float*)d_in[0];
  const float* w1       = (const float*)d_in[1];
  const float* b1       = (const float*)d_in[2];
  const float* fc1_w    = (const float*)d_in[3];
  const float* fc1_b    = (const float*)d_in[4];
  const float* fc2_w    = (const float*)d_in[5];
  const float* fc2_b    = (const float*)d_in[6];
  const float* glu_w    = (const float*)d_in[7];
  const float* glu_b    = (const float*)d_in[8];
  const float* ln_g     = (const float*)d_in[9];
  const float* ln_b     = (const float*)d_in[10];
  const float* wg_fc1_w = (const float*)d_in[11];
  const float* wg_fc1_b = (const float*)d_in[12];
  const float* wg_fc2_w = (const float*)d_in[13];
  const float* wg_fc2_b = (const float*)d_in[14];
  const float* wg_glu_w = (const float*)d_in[15];
  const float* wg_glu_b = (const float*)d_in[16];
  const float* wg_ln_g  = (const float*)d_in[17];
  const float* wg_ln_b  = (const float*)d_in[18];

  char* ws = (char*)d_ws;
  unsigned short* fc1t = (unsigned short*)ws;                       // 2 MB
  unsigned short* fc2t = fc1t + (size_t)NF * NH * ND;               // 2 MB
  unsigned short* glut = fc2t + (size_t)NF * ND * NH;               // 4 MB
  unsigned short* y2   = (unsigned short*)(ws + (8ull << 20));      // 64 MiB
  unsigned short* Hbuf = (unsigned short*)(ws + (72ull << 20));     // 64 MiB

  float* zout = (float*)d_out;                 // [NBT][ND]
  float* wout = zout + (size_t)NBT * ND;       // [NBT][16]

  wgrn_kernel<<<256, 256, 0, stream>>>(x, wg_fc1_w, wg_fc1_b, wg_fc2_w,
                                       wg_fc2_b, wg_glu_w, wg_glu_b, wg_ln_g,
                                       wg_ln_b, wout);
  transpose_all<<<dim3(16, 8, 64), dim3(32, 8), 0, stream>>>(
      fc1_w, fc2_w, glu_w, fc1t, fc2t, glut);

  g12_kernel<<<dim3(128, 16), 512, 0, stream>>>(x, w1, b1, fc1t, fc1_b, fc2t,
                                                fc2_b, y2);
  g3_kernel<<<dim3(128, 16), 512, 0, stream>>>(y2, glut, glu_b, x, w1, b1,
                                               ln_g, ln_b, Hbuf);
  combine_kernel<<<(NBT * ND / 8) / 256, 256, 0, stream>>>(Hbuf, wout, zout);

  (void)in_sizes; (void)n_in; (void)out_size; (void)ws_size;
}

// Round 20
// 194.756 us; speedup vs baseline: 1.0271x; 1.0009x over previous
//
#include <hip/hip_runtime.h>
#include <hip/hip_bf16.h>

#define NBT 8192      // B*T
#define NF  16
#define ND  256
#define NH  256
#define N2D 512

typedef short bf16x8 __attribute__((ext_vector_type(8)));
typedef float f32x4 __attribute__((ext_vector_type(4)));
typedef unsigned short u16x8 __attribute__((ext_vector_type(8)));

__device__ __forceinline__ float bf2f(unsigned short u) {
  return __uint_as_float(((unsigned)u) << 16);
}
__device__ __forceinline__ unsigned short f2bf(float f) {
  unsigned u = __float_as_uint(f);
  return (unsigned short)((u + 0x7FFFu + ((u >> 16) & 1u)) >> 16);
}

#define GLOAD16(src, dst)                                                     \
  __builtin_amdgcn_global_load_lds(                                           \
      (const __attribute__((address_space(1))) unsigned int*)(src),           \
      (__attribute__((address_space(3))) unsigned int*)(dst), 16, 0, 0)

// ---------------------------------------------------------------------------
// Weight GRN + softmax -> w [NBT][16] (fp32 exact; validated round 1)
// ---------------------------------------------------------------------------
__global__ __launch_bounds__(256) void wgrn_kernel(
    const float* __restrict__ x, const float* __restrict__ fw1,
    const float* __restrict__ fb1, const float* __restrict__ fw2,
    const float* __restrict__ fb2, const float* __restrict__ gwt,
    const float* __restrict__ gbt, const float* __restrict__ lng,
    const float* __restrict__ lnb, float* __restrict__ wout) {
  __shared__ float w1t[256 * 16];
  __shared__ float w2s[256 * 16];
  const int tid = threadIdx.x;
  for (int i = tid; i < 4096; i += 256) {
    int ff = i >> 8, j = i & 255;
    w1t[j * 16 + ff] = fw1[i];
    w2s[i] = fw2[i];
  }
  __syncthreads();
  const int sub  = tid & 7;
  const int rowi = tid >> 3;
  const int bt   = blockIdx.x * 32 + rowi;
  float xr[16];
#pragma unroll
  for (int i = 0; i < 4; ++i)
    *(float4*)&xr[i * 4] = *(const float4*)(x + (size_t)bt * 16 + i * 4);
  float acc2[16];
#pragma unroll
  for (int q = 0; q < 16; ++q) acc2[q] = 0.f;
  for (int j = sub; j < 256; j += 8) {
    float h = fb1[j];
    const float* wr = &w1t[j * 16];
#pragma unroll
    for (int q = 0; q < 16; ++q) h = fmaf(xr[q], wr[q], h);
    h = h > 0.f ? h : expm1f(h);
    const float* w2r = &w2s[j * 16];
#pragma unroll
    for (int q = 0; q < 16; ++q) acc2[q] = fmaf(h, w2r[q], acc2[q]);
  }
#pragma unroll
  for (int off = 1; off < 8; off <<= 1) {
#pragma unroll
    for (int q = 0; q < 16; ++q) acc2[q] += __shfl_xor(acc2[q], off);
  }
#pragma unroll
  for (int q = 0; q < 16; ++q) acc2[q] += fb2[q];
  float gw[32];
#pragma unroll
  for (int k = 0; k < 32; ++k) {
    float s = gbt[k];
#pragma unroll
    for (int q = 0; q < 16; ++q) s = fmaf(acc2[q], gwt[q * 32 + k], s);
    gw[k] = s;
  }
  float v[16];
  float mean = 0.f;
#pragma unroll
  for (int q = 0; q < 16; ++q) {
    float sg = 1.f / (1.f + __expf(-gw[16 + q]));
    v[q] = fmaf(gw[q], sg, xr[q]);
    mean += v[q];
  }
  mean *= (1.f / 16.f);
  float var = 0.f;
#pragma unroll
  for (int q = 0; q < 16; ++q) { float d = v[q] - mean; var = fmaf(d, d, var); }
  var *= (1.f / 16.f);
  float rstd = rsqrtf(var + 1e-5f);
  float mx = -1e30f;
#pragma unroll
  for (int q = 0; q < 16; ++q) {
    v[q] = (v[q] - mean) * rstd * lng[q] + lnb[q];
    mx = fmaxf(mx, v[q]);
  }
  float se = 0.f;
#pragma unroll
  for (int q = 0; q < 16; ++q) { v[q] = __expf(v[q] - mx); se += v[q]; }
  float inv = 1.f / se;
  if (sub == 0) {
#pragma unroll
    for (int i = 0; i < 4; ++i) {
      float4 o = { v[i*4+0]*inv, v[i*4+1]*inv, v[i*4+2]*inv, v[i*4+3]*inv };
      *(float4*)(wout + (size_t)bt * 16 + i * 4) = o;
    }
  }
}

// ---------------------------------------------------------------------------
// Fused weight prep: fp32 [K][N] -> bf16 [N][K] (validated rounds 5-19)
// ---------------------------------------------------------------------------
__global__ void transpose_all(const float* __restrict__ fc1_w,
                              const float* __restrict__ fc2_w,
                              const float* __restrict__ glu_w,
                              unsigned short* __restrict__ fc1t,
                              unsigned short* __restrict__ fc2t,
                              unsigned short* __restrict__ glut) {
  __shared__ float tile[32][33];
  const int which = blockIdx.z >> 4;
  const int f     = blockIdx.z & 15;
  const float* src;
  unsigned short* dst;
  int K, N, bx = blockIdx.x;
  if (which == 0)      { src = fc1_w; dst = fc1t; K = ND; N = NH; }
  else if (which == 1) { src = fc2_w; dst = fc2t; K = NH; N = ND; }
  else                 { src = glu_w; dst = glut; K = ND; N = N2D;
                         bx += (which == 3) ? 8 : 0; }
  if (bx * 32 >= N) return;
  const float* s = src + (size_t)f * K * N;
  unsigned short* d = dst + (size_t)f * K * N;
  const int k0 = blockIdx.y * 32, n0 = bx * 32;
  const int tx = threadIdx.x, ty = threadIdx.y;
#pragma unroll
  for (int i = 0; i < 32; i += 8)
    tile[ty + i][tx] = s[(size_t)(k0 + ty + i) * N + n0 + tx];
  __syncthreads();
#pragma unroll
  for (int i = 0; i < 32; i += 8)
    d[(size_t)(n0 + ty + i) * K + k0 + tx] = f2bf(tile[tx][ty + i]);
}

// ---------------------------------------------------------------------------
// G12 (fused g1+g2, validated rounds 15/19): y2 = (elu(h0 @ fc1^T + b1')
// @ fc2^T + b2), h0 on the fly, y1 LDS-resident. BM=64, 512 thr.
// ---------------------------------------------------------------------------
__global__ __launch_bounds__(512, 4) void g12_kernel(
    const float* __restrict__ x, const float* __restrict__ w1,
    const float* __restrict__ b1, const unsigned short* __restrict__ fc1t,
    const float* __restrict__ fc1_b, const unsigned short* __restrict__ fc2t,
    const float* __restrict__ fc2_b, unsigned short* __restrict__ y2) {
  __shared__ __align__(16) unsigned short hbuf[64 * 264];  // 33792 B
  __shared__ __align__(16) unsigned short bstg[256 * 64];  // 32768 B
  __shared__ float xw[64];
  const int tid = threadIdx.x, lane = tid & 63, wid = tid >> 6;
  const int rl = lane & 15, kc = lane >> 4;
  int hb = blockIdx.x + 128 * blockIdx.y;
  int L  = (hb & 7) * 256 + (hb >> 3);
  const int f = L >> 7, m0 = (L & 127) * 64;
  const unsigned short* B1 = fc1t + (size_t)f * NH * ND;  // [256][256]
  const unsigned short* B2 = fc2t + (size_t)f * ND * NH;  // [256][256]
  const float* w1f = w1 + f * ND;
  const float* b1f = b1 + f * ND;
  const int wn = wid * 32;

  if (tid < 64) xw[tid] = x[(size_t)(m0 + tid) * NF + f];
  __syncthreads();

#pragma unroll
  for (int i = 0; i < 4; ++i) {
    int j = tid + 512 * i;
    int row = j >> 5, c = (j & 31) * 8;
    float xv = xw[row];
    float4 wa = *(const float4*)(w1f + c);
    float4 wb = *(const float4*)(w1f + c + 4);
    float4 ba = *(const float4*)(b1f + c);
    float4 bb = *(const float4*)(b1f + c + 4);
    u16x8 o;
    o[0] = f2bf(fmaxf(fmaf(xv, wa.x, ba.x), 0.f));
    o[1] = f2bf(fmaxf(fmaf(xv, wa.y, ba.y), 0.f));
    o[2] = f2bf(fmaxf(fmaf(xv, wa.z, ba.z), 0.f));
    o[3] = f2bf(fmaxf(fmaf(xv, wa.w, ba.w), 0.f));
    o[4] = f2bf(fmaxf(fmaf(xv, wb.x, bb.x), 0.f));
    o[5] = f2bf(fmaxf(fmaf(xv, wb.y, bb.y), 0.f));
    o[6] = f2bf(fmaxf(fmaf(xv, wb.z, bb.z), 0.f));
    o[7] = f2bf(fmaxf(fmaf(xv, wb.w, bb.w), 0.f));
    *(u16x8*)(hbuf + row * 264 + c) = o;
  }
  __syncthreads();

  f32x4 acc[4][2];
#pragma unroll
  for (int m = 0; m < 4; ++m)
#pragma unroll
    for (int n = 0; n < 2; ++n) acc[m][n] = (f32x4){0.f, 0.f, 0.f, 0.f};

  for (int kt = 0; kt < ND; kt += 64) {
    if (kt) __syncthreads();
#pragma unroll
    for (int i = 0; i < 4; ++i) {
      int s = tid + 512 * i;
      int row = s >> 3, sl = s & 7;
      GLOAD16(B1 + (size_t)row * ND + kt + ((sl ^ (row & 7)) << 3),
              (char*)bstg + (wid * 64 + 512 * i) * 16);
    }
    __syncthreads();
#pragma unroll
    for (int kk = 0; kk < 2; ++kk) {
      int s = kk * 4 + kc;
      bf16x8 av[4], bv[2];
#pragma unroll
      for (int n = 0; n < 2; ++n) {
        int rr = wn + n * 16 + rl;
        int ps = s ^ (rr & 7);
        bv[n] = *(const bf16x8*)((const char*)bstg + rr * 128 + ps * 16);
      }
#pragma unroll
      for (int m = 0; m < 4; ++m)
        av[m] = *(const bf16x8*)(hbuf + (m * 16 + rl) * 264 + kt + s * 8);
#pragma unroll
      for (int m = 0; m < 4; ++m)
#pragma unroll
        for (int n = 0; n < 2; ++n)
          acc[m][n] = __builtin_amdgcn_mfma_f32_16x16x32_bf16(av[m], bv[n],
                                                              acc[m][n], 0, 0, 0);
    }
  }
  __syncthreads();

#pragma unroll
  for (int n = 0; n < 2; ++n) {
    int c = wn + n * 16 + rl;
    float bvv = fc1_b[f * NH + c];
#pragma unroll
    for (int m = 0; m < 4; ++m) {
#pragma unroll
      for (int j = 0; j < 4; ++j) {
        int r = m * 16 + kc * 4 + j;
        float v = acc[m][n][j] + bvv;
        v = v > 0.f ? v : expm1f(v);
        hbuf[r * 264 + c] = f2bf(v);
      }
    }
  }
  __syncthreads();

#pragma unroll
  for (int m = 0; m < 4; ++m)
#pragma unroll
    for (int n = 0; n < 2; ++n) acc[m][n] = (f32x4){0.f, 0.f, 0.f, 0.f};

  for (int kt = 0; kt < NH; kt += 64) {
    if (kt) __syncthreads();
#pragma unroll
    for (int i = 0; i < 4; ++i) {
      int s = tid + 512 * i;
      int row = s >> 3, sl = s & 7;
      GLOAD16(B2 + (size_t)row * NH + kt + ((sl ^ (row & 7)) << 3),
              (char*)bstg + (wid * 64 + 512 * i) * 16);
    }
    __syncthreads();
#pragma unroll
    for (int kk = 0; kk < 2; ++kk) {
      int s = kk * 4 + kc;
      bf16x8 av[4], bv[2];
#pragma unroll
      for (int n = 0; n < 2; ++n) {
        int rr = wn + n * 16 + rl;
        int ps = s ^ (rr & 7);
        bv[n] = *(const bf16x8*)((const char*)bstg + rr * 128 + ps * 16);
      }
#pragma unroll
      for (int m = 0; m < 4; ++m)
        av[m] = *(const bf16x8*)(hbuf + (m * 16 + rl) * 264 + kt + s * 8);
#pragma unroll
      for (int m = 0; m < 4; ++m)
#pragma unroll
        for (int n = 0; n < 2; ++n)
          acc[m][n] = __builtin_amdgcn_mfma_f32_16x16x32_bf16(av[m], bv[n],
                                                              acc[m][n], 0, 0, 0);
    }
  }
  __syncthreads();

#pragma unroll
  for (int n = 0; n < 2; ++n) {
    int c = wn + n * 16 + rl;
    float bvv = fc2_b[f * ND + c];
#pragma unroll
    for (int m = 0; m < 4; ++m) {
#pragma unroll
      for (int j = 0; j < 4; ++j) {
        int r = m * 16 + kc * 4 + j;
        hbuf[r * 264 + c] = f2bf(acc[m][n][j] + bvv);
      }
    }
  }
  __syncthreads();
#pragma unroll
  for (int v = 0; v < 4; ++v) {
    int job = tid + 512 * v;
    int row = job >> 5, ch = job & 31;
    u16x8 val = *(const u16x8*)(hbuf + row * 264 + ch * 8);
    *(u16x8*)(y2 + ((size_t)f * NBT + m0 + row) * ND + ch * 8) = val;
  }
}

// ---------------------------------------------------------------------------
// G3 (r15 verbatim except H layout): a|gate = y2 @ glu^T + b;
// v = h0 + a*sig(gate); LN -> H stored [bt][f][d] (combine-friendly).
// ---------------------------------------------------------------------------
__global__ __launch_bounds__(512, 4) void g3_kernel(
    const unsigned short* __restrict__ y2,
    const unsigned short* __restrict__ glut, const float* __restrict__ glu_b,
    const float* __restrict__ x, const float* __restrict__ w1,
    const float* __restrict__ b1, const float* __restrict__ ln_g,
    const float* __restrict__ ln_b, unsigned short* __restrict__ H) {
  __shared__ __align__(16) char arena[73728];  // A 8K + B 64K | vbuf 33792
  __shared__ float xw[64];
  __shared__ float2 sums[8][64];
  __shared__ float2 sums2[64];
  unsigned short* abuf = (unsigned short*)arena;            // [64][64]
  unsigned short* bbuf = (unsigned short*)(arena + 8192);   // [512][64]
  unsigned short* vbuf = (unsigned short*)arena;            // [64][264]

  const int tid = threadIdx.x, lane = tid & 63, wid = tid >> 6;
  const int rl = lane & 15, rq = lane >> 4;
  int hb = blockIdx.x + 128 * blockIdx.y;
  int L  = (hb & 7) * 256 + (hb >> 3);
  const int f = L >> 7, m0 = (L & 127) * 64;
  const unsigned short* Af = y2 + (size_t)f * NBT * ND;
  const unsigned short* Bf = glut + (size_t)f * ND * N2D;  // [512][256]
  const float* w1f = w1 + f * ND;
  const float* b1f = b1 + f * ND;
  const int colb = wid * 32;
  if (tid < 64) xw[tid] = x[(size_t)(m0 + tid) * NF + f];

  f32x4 acc[4][4];
#pragma unroll
  for (int m = 0; m < 4; ++m)
#pragma unroll
    for (int n = 0; n < 4; ++n) acc[m][n] = (f32x4){0.f, 0.f, 0.f, 0.f};

  for (int kt = 0; kt < ND; kt += 64) {
    __syncthreads();
    {  // A [64][64]
      int s = tid;
      int row = s >> 3, sl = s & 7;
      const unsigned short* ga =
          Af + (size_t)(m0 + row) * ND + kt + ((sl ^ (row & 7)) << 3);
      GLOAD16(ga, (char*)abuf + (wid * 64) * 16);
    }
#pragma unroll
    for (int i = 0; i < 8; ++i) {  // B [512][64]
      int s = tid + 512 * i;
      int row = s >> 3, sl = s & 7;
      const unsigned short* gb =
          Bf + (size_t)row * ND + kt + ((sl ^ (row & 7)) << 3);
      GLOAD16(gb, (char*)bbuf + (wid * 64 + 512 * i) * 16);
    }
    __syncthreads();
#pragma unroll
    for (int kk = 0; kk < 2; ++kk) {
      bf16x8 av[4], bv[4];
      int s = kk * 4 + rq;
#pragma unroll
      for (int m = 0; m < 4; ++m) {
        int r = m * 16 + rl;
        int ps = s ^ (r & 7);
        av[m] = *(const bf16x8*)((const char*)abuf + r * 128 + ps * 16);
      }
#pragma unroll
      for (int n = 0; n < 4; ++n) {
        int rr = (n < 2) ? (colb + n * 16 + rl)
                         : (256 + colb + (n - 2) * 16 + rl);
        int ps = s ^ (rr & 7);
        bv[n] = *(const bf16x8*)((const char*)bbuf + rr * 128 + ps * 16);
      }
#pragma unroll
      for (int m = 0; m < 4; ++m)
#pragma unroll
        for (int n = 0; n < 4; ++n)
          acc[m][n] = __builtin_amdgcn_mfma_f32_16x16x32_bf16(av[m], bv[n],
                                                              acc[m][n], 0, 0, 0);
    }
  }

#pragma unroll
  for (int n = 0; n < 2; ++n) {
    int cA = colb + n * 16 + rl;
    float ab_ = glu_b[f * N2D + cA];
    float gb_ = glu_b[f * N2D + 256 + cA];
    float w1c = w1f[cA], b1c = b1f[cA];
#pragma unroll
    for (int m = 0; m < 4; ++m) {
#pragma unroll
      for (int j = 0; j < 4; ++j) {
        int r = m * 16 + rq * 4 + j;
        float a = acc[m][n][j] + ab_;
        float g = acc[m][n + 2][j] + gb_;
        float sg = 1.f / (1.f + __expf(-g));
        float h0 = fmaxf(fmaf(xw[r], w1c, b1c), 0.f);
        acc[m][n][j] = fmaf(a, sg, h0);
      }
    }
  }
#pragma unroll
  for (int m = 0; m < 4; ++m) {
#pragma unroll
    for (int j = 0; j < 4; ++j) {
      float s = acc[m][0][j] + acc[m][1][j];
      float q = fmaf(acc[m][0][j], acc[m][0][j],
                     acc[m][1][j] * acc[m][1][j]);
#pragma unroll
      for (int off = 1; off < 16; off <<= 1) {
        s += __shfl_xor(s, off);
        q += __shfl_xor(q, off);
      }
      if (rl == 0) sums[wid][m * 16 + rq * 4 + j] = make_float2(s, q);
    }
  }
  __syncthreads();
  if (tid < 64) {
    float tot = 0.f, tot2 = 0.f;
#pragma unroll
    for (int wv = 0; wv < 8; ++wv) {
      float2 p = sums[wv][tid];
      tot += p.x;
      tot2 += p.y;
    }
    float mean = tot * (1.f / 256.f);
    float var  = tot2 * (1.f / 256.f) - mean * mean;
    sums2[tid] = make_float2(mean, rsqrtf(var + 1e-5f));
  }
  __syncthreads();
#pragma unroll
  for (int n = 0; n < 2; ++n) {
    int cA = colb + n * 16 + rl;
    float lg = ln_g[f * ND + cA], lb = ln_b[f * ND + cA];
#pragma unroll
    for (int m = 0; m < 4; ++m) {
#pragma unroll
      for (int j = 0; j < 4; ++j) {
        int r = m * 16 + rq * 4 + j;
        float2 mr = sums2[r];
        vbuf[r * 264 + cA] = f2bf(fmaf((acc[m][n][j] - mr.x) * mr.y, lg, lb));
      }
    }
  }
  __syncthreads();
  {
    // H layout [bt][f][d]: row (m0+row) -> offset ((m0+row)*NF + f)*ND
    int row = tid >> 3, chunk = tid & 7;
    unsigned short* Hrow = H + ((size_t)(m0 + row) * NF + f) * ND;
#pragma unroll
    for (int v = 0; v < 4; ++v) {
      u16x8 val = *(const u16x8*)(vbuf + row * 264 + chunk * 8 + v * 64);
      *(u16x8*)(Hrow + chunk * 8 + v * 64) = val;
    }
  }
}

// ---------------------------------------------------------------------------
// z[bt][d] = sum_f H[bt][f][d] * w[bt][f]  (contiguous 8KB stream per bt)
// ---------------------------------------------------------------------------
__global__ __launch_bounds__(256) void combine_kernel(
    const unsigned short* __restrict__ H, const float* __restrict__ w,
    float* __restrict__ z) {
  int idx = blockIdx.x * 256 + threadIdx.x;
  int bt = idx >> 5;
  int d  = (idx & 31) << 3;
  const unsigned short* Hbt = H + (size_t)bt * NF * ND;
  float a[8];
#pragma unroll
  for (int j = 0; j < 8; ++j) a[j] = 0.f;
#pragma unroll
  for (int f = 0; f < 16; ++f) {
    u16x8 hv = *(const u16x8*)(Hbt + f * ND + d);
    float wvv = w[bt * 16 + f];
#pragma unroll
    for (int j = 0; j < 8; ++j) a[j] = fmaf(bf2f(hv[j]), wvv, a[j]);
  }
  float4 o0 = {a[0], a[1], a[2], a[3]};
  float4 o1 = {a[4], a[5], a[6], a[7]};
  *(float4*)(z + (size_t)bt * ND + d)     = o0;
  *(float4*)(z + (size_t)bt * ND + d + 4) = o1;
}

// ---------------------------------------------------------------------------
extern "C" void kernel_launch(void* const* d_in, const int* in_sizes, int n_in,
                              void* d_out, int out_size, void* d_ws,
                              size_t ws_size, hipStream_t stream) {
  const float* x        = (const float*)d_in[0];
  const float* w1       = (const float*)d_in[1];
  const float* b1       = (const float*)d_in[2];
  const float* fc1_w    = (const float*)d_in[3];
  const float* fc1_b    = (const float*)d_in[4];
  const float* fc2_w    = (const float*)d_in[5];
  const float* fc2_b    = (const float*)d_in[6];
  const float* glu_w    = (const float*)d_in[7];
  const float* glu_b    = (const float*)d_in[8];
  const float* ln_g     = (const float*)d_in[9];
  const float* ln_b     = (const float*)d_in[10];
  const float* wg_fc1_w = (const float*)d_in[11];
  const float* wg_fc1_b = (const float*)d_in[12];
  const float* wg_fc2_w = (const float*)d_in[13];
  const float* wg_fc2_b = (const float*)d_in[14];
  const float* wg_glu_w = (const float*)d_in[15];
  const float* wg_glu_b = (const float*)d_in[16];
  const float* wg_ln_g  = (const float*)d_in[17];
  const float* wg_ln_b  = (const float*)d_in[18];

  char* ws = (char*)d_ws;
  unsigned short* fc1t = (unsigned short*)ws;                       // 2 MB
  unsigned short* fc2t = fc1t + (size_t)NF * NH * ND;               // 2 MB
  unsigned short* glut = fc2t + (size_t)NF * ND * NH;               // 4 MB
  unsigned short* y2   = (unsigned short*)(ws + (8ull << 20));      // 64 MiB
  unsigned short* Hbuf = (unsigned short*)(ws + (72ull << 20));     // 64 MiB

  float* zout = (float*)d_out;                 // [NBT][ND]
  float* wout = zout + (size_t)NBT * ND;       // [NBT][16]

  wgrn_kernel<<<256, 256, 0, stream>>>(x, wg_fc1_w, wg_fc1_b, wg_fc2_w,
                                       wg_fc2_b, wg_glu_w, wg_glu_b, wg_ln_g,
                                       wg_ln_b, wout);
  transpose_all<<<dim3(16, 8, 64), dim3(32, 8), 0, stream>>>(
      fc1_w, fc2_w, glu_w, fc1t, fc2t, glut);

  g12_kernel<<<dim3(128, 16), 512, 0, stream>>>(x, w1, b1, fc1t, fc1_b, fc2t,
                                                fc2_b, y2);
  g3_kernel<<<dim3(128, 16), 512, 0, stream>>>(y2, glut, glu_b, x, w1, b1,
                                               ln_g, ln_b, Hbuf);
  combine_kernel<<<(NBT * ND / 8) / 256, 256, 0, stream>>>(Hbuf, wout, zout);

  (void)in_sizes; (void)n_in; (void)out_size; (void)ws_size;
}